// Round 13
// baseline (140.431 us; speedup 1.0000x reference)
//
#include <hip/hip_runtime.h>

#define N_NODES 50000
#define HIDDEN 128
#define NBUCK ((N_NODES + 127) >> 7)  // 391 coarse buckets of 128 dst nodes
#define BCAP 2304                     // slack capacity per bucket (mean 2048 + 5.7 sigma)
#define CAST_BLOCKS 6250              // 1.6M ushort4 elements / 256

typedef __attribute__((ext_vector_type(8))) short short8;
typedef __attribute__((ext_vector_type(4))) float f32x4;

__device__ __forceinline__ unsigned short f2bf(float f) {
    union { float f; unsigned int u; } a; a.f = f;
    unsigned int u = a.u;
    u += 0x7FFFu + ((u >> 16) & 1u);  // RNE
    return (unsigned short)(u >> 16);
}
__device__ __forceinline__ float bf2f(unsigned int bits16) {
    union { unsigned int u; float f; } a; a.u = bits16 << 16;
    return a.f;
}

// Fused prep: blocks [0,CAST_BLOCKS) cast x->bf16; blocks [CAST_BLOCKS, +256)
// pack both layers' Wcat[256][128] (rows 0..127 = Wl^T, 128..255 = Wr^T) into
// MFMA-B fragment order and init slack-allocator cursors bcur[b]=b*BCAP.
// Wp[((ks*8+nf)*64+lane)*8+j] = Wcat[ks*32+(lane>>4)*8+j][nf*16+(lane&15)]
__global__ __launch_bounds__(256) void prep(
    const float* __restrict__ x, unsigned short* __restrict__ xb,
    const float* __restrict__ W1l, const float* __restrict__ W1r,
    const float* __restrict__ W2l, const float* __restrict__ W2r,
    unsigned short* __restrict__ Wp1, unsigned short* __restrict__ Wp2,
    int* __restrict__ bcur) {
    const int b = blockIdx.x;
    if (b < CAST_BLOCKS) {
        const int i = b * 256 + threadIdx.x;  // < 1.6M
        float4 v = reinterpret_cast<const float4*>(x)[i];
        ushort4 o = make_ushort4(f2bf(v.x), f2bf(v.y), f2bf(v.z), f2bf(v.w));
        reinterpret_cast<ushort4*>(xb)[i] = o;
        return;
    }
    const int tid = (b - CAST_BLOCKS) * 256 + threadIdx.x;  // < 65536
    if (tid < NBUCK) bcur[tid] = tid * BCAP;
    const int which = tid >> 15;                      // 0 -> layer1, 1 -> layer2
    const int t2 = tid & 32767;
    int j = t2 & 7, lane = (t2 >> 3) & 63, nf = (t2 >> 9) & 7, ks = t2 >> 12;
    int k = ks * 32 + ((lane >> 4) * 8) + j;
    int t = nf * 16 + (lane & 15);
    const float* Wl = which ? W2l : W1l;
    const float* Wr = which ? W2r : W1r;
    float v = (k < 128) ? Wl[t * 128 + k] : Wr[t * 128 + (k - 128)];
    (which ? Wp2 : Wp1)[t2] = f2bf(v);
}

// Block-aggregated partition into slack-capacity buckets: each block reserves
// per-bucket ranges with ONE global atomic per (block,bucket), then scatters
// packed (dst<<16)|src via LDS cursors. No pre-histogram/scan needed.
// PCHUNK=4096 (196 blocks): halves the per-address serialization depth of the
// 391 bcur reservation atomics vs PCHUNK=2048 (R5/R12 lesson).
#define PCHUNK 4096  // edges per block (1024 threads x 4)
__global__ __launch_bounds__(1024) void partition_edges(
    const int* __restrict__ src, const int* __restrict__ dst, int E,
    int* __restrict__ bcur, unsigned int* __restrict__ packed) {
    __shared__ int h[NBUCK];     // local hist, then local cursor
    __shared__ int base[NBUCK];  // reserved global base per bucket
    const int tid = threadIdx.x;
    const int c0 = blockIdx.x * PCHUNK;
    for (int i = tid; i < NBUCK; i += 1024) h[i] = 0;
    __syncthreads();

    unsigned int val[4];
    int bk[4];
#pragma unroll
    for (int u = 0; u < 4; ++u) {
        const int e = c0 + u * 1024 + tid;
        if (e < E) {
            const int d = dst[e];
            val[u] = ((unsigned int)d << 16) | (unsigned int)src[e];
            bk[u] = d >> 7;
            atomicAdd(&h[bk[u]], 1);
        } else {
            bk[u] = -1;
        }
    }
    __syncthreads();
    for (int i = tid; i < NBUCK; i += 1024) {
        base[i] = h[i] ? atomicAdd(&bcur[i], h[i]) : 0;
        h[i] = 0;  // reuse as local cursor
    }
    __syncthreads();
#pragma unroll
    for (int u = 0; u < 4; ++u) {
        if (bk[u] >= 0) {
            const int pos = base[bk[u]] + atomicAdd(&h[bk[u]], 1);
            packed[pos] = val[u];
        }
    }
}

// One block per bucket: LDS 128-bin hist + scan -> per-node row_start/row_end;
// LDS-cursor scatter of u16 srcs into the bucket's contiguous region.
__global__ __launch_bounds__(512) void build_rows(const unsigned int* __restrict__ packed,
                                                  const int* __restrict__ bcur,
                                                  int* __restrict__ row_start,
                                                  int* __restrict__ row_end,
                                                  unsigned short* __restrict__ ssrc) {
    __shared__ int lh[128];
    __shared__ int lc[128];
    __shared__ int htot;
    const int b = blockIdx.x;
    const int gbase = b * BCAP, gend = bcur[b];
    const int tid = threadIdx.x;
    if (tid < 128) lh[tid] = 0;
    __syncthreads();
    for (int i = gbase + tid; i < gend; i += 512)
        atomicAdd(&lh[(packed[i] >> 16) & 127], 1);
    __syncthreads();
    int v = 0, incl = 0;
    if (tid < 128) {
        const int lane = tid & 63;
        v = lh[tid];
        incl = v;
#pragma unroll
        for (int off = 1; off < 64; off <<= 1) {
            int t = __shfl_up(incl, off);
            if (lane >= off) incl += t;
        }
        if (tid == 63) htot = incl;
    }
    __syncthreads();
    if (tid < 128) {
        const int excl = incl - v + ((tid >= 64) ? htot : 0);
        lc[tid] = gbase + excl;
        const int node = b * 128 + tid;
        if (node < N_NODES) {
            row_start[node] = gbase + excl;
            row_end[node]   = gbase + excl + v;
        }
    }
    __syncthreads();
    for (int i = gbase + tid; i < gend; i += 512) {
        const unsigned int p = packed[i];
        const int pos = atomicAdd(&lc[(p >> 16) & 127], 1);
        ssrc[pos] = (unsigned short)(p & 0xffffu);
    }
}

// 16 lanes per node (lane owns 8 features via ushort8 = 16B), 4 nodes per wave,
// edge loop unroll 8 -> up to 32 row-gathers in flight per wave.
__global__ __launch_bounds__(256) void aggregate_mean_bf16(
    const unsigned short* __restrict__ featb, const int* __restrict__ row_start,
    const int* __restrict__ row_end, const unsigned short* __restrict__ ssrc,
    unsigned short* __restrict__ aggb) {
    const int node = blockIdx.x * 16 + (threadIdx.x >> 4);
    const int lq = threadIdx.x & 15;
    if (node >= N_NODES) return;
    const int beg = row_start[node], end = row_end[node];
    float acc0[8], acc1[8];
#pragma unroll
    for (int f = 0; f < 8; ++f) { acc0[f] = 0.f; acc1[f] = 0.f; }

    int j = beg;
    for (; j + 7 < end; j += 8) {
        short8 v[8];
#pragma unroll
        for (int u = 0; u < 8; ++u) {
            const int s = ssrc[j + u];
            v[u] = *reinterpret_cast<const short8*>(&featb[(size_t)s * HIDDEN + 8 * lq]);
        }
#pragma unroll
        for (int u = 0; u < 8; ++u) {
            float* a = (u & 1) ? acc1 : acc0;
#pragma unroll
            for (int f = 0; f < 8; ++f) a[f] += bf2f((unsigned short)v[u][f]);
        }
    }
    if (j + 3 < end) {
        short8 v[4];
#pragma unroll
        for (int u = 0; u < 4; ++u) {
            const int s = ssrc[j + u];
            v[u] = *reinterpret_cast<const short8*>(&featb[(size_t)s * HIDDEN + 8 * lq]);
        }
#pragma unroll
        for (int u = 0; u < 4; ++u) {
            float* a = (u & 1) ? acc1 : acc0;
#pragma unroll
            for (int f = 0; f < 8; ++f) a[f] += bf2f((unsigned short)v[u][f]);
        }
        j += 4;
    }
    for (; j < end; ++j) {
        const int s = ssrc[j];
        const short8 v = *reinterpret_cast<const short8*>(&featb[(size_t)s * HIDDEN + 8 * lq]);
#pragma unroll
        for (int f = 0; f < 8; ++f) acc0[f] += bf2f((unsigned short)v[f]);
    }
    const int d = end - beg;
    const float inv = d ? 1.0f / (float)d : 0.0f;
    short8 o;
#pragma unroll
    for (int f = 0; f < 8; ++f) o[f] = (short)f2bf((acc0[f] + acc1[f]) * inv);
    *reinterpret_cast<short8*>(&aggb[(size_t)node * HIDDEN + 8 * lq]) = o;
}

// out[n][t] = relu?( sum_k aggb[n][k]*Wl[t][k] + xb[n][k]*Wr[t][k] + b[t] )
// 32-row x 128-col tile, 4 waves (wm: 16-row half, wn: 64-col half).
// Grid 1563 blocks -> 24 waves/CU (was 782 -> 12): the kernel was TLP-starved
// (latency-bound at 3 waves/SIMD with VGPRs permitting 8) — R12 analysis.
// Per wave per ks: 1 A-frag + 4 B-frags, depth-1 prefetch.
// Layer 1 (WRITE_BF16_RELU=1) writes bf16 IN-PLACE over xb: each block reads
// only its own 32 rows before its epilogue stores -> no hazard.
template <int WRITE_BF16_RELU>
__global__ __launch_bounds__(256) void mfma_linear(
    const unsigned short* aggb, const unsigned short* xb,
    const unsigned short* __restrict__ Wp, const float* __restrict__ bias,
    unsigned short* out_b, float* out_f) {
    const int lane = threadIdx.x & 63;
    const int wave = threadIdx.x >> 6;
    const int wm = wave >> 1, wn = wave & 1;
    const int rowbase = blockIdx.x * 32 + wm * 16;
    const int colbase = wn * 64;
    const int l15 = lane & 15, l4 = lane >> 4;

    // clamped row address (constant across ks)
    int rowc = rowbase + l15;
    if (rowc >= N_NODES) rowc = N_NODES - 1;
    const size_t rowoff = (size_t)rowc * HIDDEN;
    const unsigned short* wpbase = &Wp[(((size_t)(colbase >> 4)) * 64 + lane) * 8];

    f32x4 acc[4];
#pragma unroll
    for (int nf = 0; nf < 4; ++nf) acc[nf] = (f32x4){0.f, 0.f, 0.f, 0.f};

    short8 a_cur, a_nxt, b_cur[4], b_nxt[4];

#define LOAD_A(dst, ksv)                                                          \
    {                                                                             \
        const unsigned short* Asrc_ = ((ksv) < 4) ? aggb : xb;                    \
        const int koff_ = ((ksv) & 3) * 32 + l4 * 8;                              \
        dst = *reinterpret_cast<const short8*>(&Asrc_[rowoff + koff_]);           \
    }
#define LOAD_B(dst, ksv)                                                          \
    {                                                                             \
        _Pragma("unroll")                                                         \
        for (int nf_ = 0; nf_ < 4; ++nf_)                                         \
            dst[nf_] = *reinterpret_cast<const short8*>(                          \
                &wpbase[((size_t)(ksv)*8 + nf_) * 64 * 8]);                       \
    }

    LOAD_A(a_cur, 0);
    LOAD_B(b_cur, 0);

#pragma unroll
    for (int ks = 0; ks < 8; ++ks) {
        if (ks < 7) {
            LOAD_A(a_nxt, ks + 1);
            LOAD_B(b_nxt, ks + 1);
        }
#pragma unroll
        for (int nf = 0; nf < 4; ++nf)
            acc[nf] = __builtin_amdgcn_mfma_f32_16x16x32_bf16(a_cur, b_cur[nf], acc[nf], 0, 0, 0);
        if (ks < 7) {
            a_cur = a_nxt;
#pragma unroll
            for (int nf = 0; nf < 4; ++nf) b_cur[nf] = b_nxt[nf];
        }
    }
#undef LOAD_A
#undef LOAD_B

#pragma unroll
    for (int nf = 0; nf < 4; ++nf) {
        const int col = colbase + nf * 16 + l15;
        const float bv = bias[col];
#pragma unroll
        for (int r = 0; r < 4; ++r) {
            const int row = rowbase + l4 * 4 + r;
            if (row < N_NODES) {
                float v = acc[nf][r] + bv;
                if (WRITE_BF16_RELU) {
                    v = fmaxf(v, 0.0f);
                    out_b[(size_t)row * HIDDEN + col] = f2bf(v);
                } else {
                    out_f[(size_t)row * HIDDEN + col] = v;
                }
            }
        }
    }
}

extern "C" void kernel_launch(void* const* d_in, const int* in_sizes, int n_in,
                              void* d_out, int out_size, void* d_ws, size_t ws_size,
                              hipStream_t stream) {
    const float* x   = (const float*)d_in[0];
    const int*   ei  = (const int*)d_in[1];
    const float* W1l = (const float*)d_in[2];
    const float* b1  = (const float*)d_in[3];
    const float* W1r = (const float*)d_in[4];
    const float* W2l = (const float*)d_in[5];
    const float* b2  = (const float*)d_in[6];
    const float* W2r = (const float*)d_in[7];

    const int E = in_sizes[1] / 2;
    const int* src = ei;
    const int* dst = ei + E;

    // ---- workspace layout (all sections 16B aligned) ----
    int* iws        = (int*)d_ws;
    int* bcur       = iws;                       // @0      391 (pad 400)
    int* row_start  = iws + 400;                 // @400    50000
    int* row_end    = iws + 50400;               // @50400  50000
    unsigned int* packed = (unsigned int*)(iws + 100400);          // NBUCK*BCAP u32
    unsigned short* ssrc = (unsigned short*)(iws + 100400 + NBUCK * BCAP);  // NBUCK*BCAP u16
    unsigned short* xb   = ssrc + (size_t)NBUCK * BCAP;  // 6.4M bf16 (h overwrites in-place)
    unsigned short* aggb = xb + (size_t)N_NODES * HIDDEN;          // 6.4M bf16
    unsigned short* Wp1  = aggb + (size_t)N_NODES * HIDDEN;        // 32768 bf16
    unsigned short* Wp2  = Wp1 + 256 * HIDDEN;                     // 32768 bf16

    // prep: cast + pack + bcur init, one dispatch
    prep<<<CAST_BLOCKS + 256, 256, 0, stream>>>(x, xb, W1l, W1r, W2l, W2r, Wp1, Wp2, bcur);

    // ---- CSR build (shared by both layers): 2 kernels, no hist/scan ----
    partition_edges<<<(E + PCHUNK - 1) / PCHUNK, 1024, 0, stream>>>(src, dst, E, bcur, packed);
    build_rows<<<NBUCK, 512, 0, stream>>>(packed, bcur, row_start, row_end, ssrc);

    const int aggGrid = (N_NODES + 15) / 16;
    const int linGrid = (N_NODES + 31) / 32;

    // ---- layer 1 ----
    aggregate_mean_bf16<<<aggGrid, 256, 0, stream>>>(xb, row_start, row_end, ssrc, aggb);
    mfma_linear<1><<<linGrid, 256, 0, stream>>>(aggb, xb, Wp1, b1, xb, nullptr);

    // ---- layer 2 ----
    aggregate_mean_bf16<<<aggGrid, 256, 0, stream>>>(xb, row_start, row_end, ssrc, aggb);
    mfma_linear<0><<<linGrid, 256, 0, stream>>>(aggb, xb, Wp2, b2, nullptr, (float*)d_out);
}

// Round 14
// 138.034 us; speedup vs baseline: 1.0174x; 1.0174x over previous
//
#include <hip/hip_runtime.h>

#define N_NODES 50000
#define HIDDEN 128
#define NBUCK ((N_NODES + 127) >> 7)  // 391 coarse buckets of 128 dst nodes
#define BCAP 2304                     // slack capacity per bucket (mean 2048 + 5.7 sigma)
#define CAST_BLOCKS 6250              // 1.6M ushort4 elements / 256

typedef __attribute__((ext_vector_type(8))) short short8;
typedef __attribute__((ext_vector_type(4))) float f32x4;

__device__ __forceinline__ unsigned short f2bf(float f) {
    union { float f; unsigned int u; } a; a.f = f;
    unsigned int u = a.u;
    u += 0x7FFFu + ((u >> 16) & 1u);  // RNE
    return (unsigned short)(u >> 16);
}
__device__ __forceinline__ float bf2f(unsigned int bits16) {
    union { unsigned int u; float f; } a; a.u = bits16 << 16;
    return a.f;
}

// Fused prep: blocks [0,CAST_BLOCKS) cast x->bf16; blocks [CAST_BLOCKS, +256)
// pack both layers' Wcat[256][128] (rows 0..127 = Wl^T, 128..255 = Wr^T) into
// MFMA-B fragment order and init slack-allocator cursors bcur[b]=b*BCAP.
// Wp[((ks*8+nf)*64+lane)*8+j] = Wcat[ks*32+(lane>>4)*8+j][nf*16+(lane&15)]
__global__ __launch_bounds__(256) void prep(
    const float* __restrict__ x, unsigned short* __restrict__ xb,
    const float* __restrict__ W1l, const float* __restrict__ W1r,
    const float* __restrict__ W2l, const float* __restrict__ W2r,
    unsigned short* __restrict__ Wp1, unsigned short* __restrict__ Wp2,
    int* __restrict__ bcur) {
    const int b = blockIdx.x;
    if (b < CAST_BLOCKS) {
        const int i = b * 256 + threadIdx.x;  // < 1.6M
        float4 v = reinterpret_cast<const float4*>(x)[i];
        ushort4 o = make_ushort4(f2bf(v.x), f2bf(v.y), f2bf(v.z), f2bf(v.w));
        reinterpret_cast<ushort4*>(xb)[i] = o;
        return;
    }
    const int tid = (b - CAST_BLOCKS) * 256 + threadIdx.x;  // < 65536
    if (tid < NBUCK) bcur[tid] = tid * BCAP;
    const int which = tid >> 15;                      // 0 -> layer1, 1 -> layer2
    const int t2 = tid & 32767;
    int j = t2 & 7, lane = (t2 >> 3) & 63, nf = (t2 >> 9) & 7, ks = t2 >> 12;
    int k = ks * 32 + ((lane >> 4) * 8) + j;
    int t = nf * 16 + (lane & 15);
    const float* Wl = which ? W2l : W1l;
    const float* Wr = which ? W2r : W1r;
    float v = (k < 128) ? Wl[t * 128 + k] : Wr[t * 128 + (k - 128)];
    (which ? Wp2 : Wp1)[t2] = f2bf(v);
}

// Block-aggregated partition into slack-capacity buckets: each block reserves
// per-bucket ranges with ONE global atomic per (block,bucket), then scatters
// packed (dst<<16)|src via LDS cursors. No pre-histogram/scan needed.
// PCHUNK=4096 (196 blocks): halves the per-address serialization depth of the
// 391 bcur reservation atomics vs PCHUNK=2048 (R5/R12 lesson).
#define PCHUNK 4096  // edges per block (1024 threads x 4)
__global__ __launch_bounds__(1024) void partition_edges(
    const int* __restrict__ src, const int* __restrict__ dst, int E,
    int* __restrict__ bcur, unsigned int* __restrict__ packed) {
    __shared__ int h[NBUCK];     // local hist, then local cursor
    __shared__ int base[NBUCK];  // reserved global base per bucket
    const int tid = threadIdx.x;
    const int c0 = blockIdx.x * PCHUNK;
    for (int i = tid; i < NBUCK; i += 1024) h[i] = 0;
    __syncthreads();

    unsigned int val[4];
    int bk[4];
#pragma unroll
    for (int u = 0; u < 4; ++u) {
        const int e = c0 + u * 1024 + tid;
        if (e < E) {
            const int d = dst[e];
            val[u] = ((unsigned int)d << 16) | (unsigned int)src[e];
            bk[u] = d >> 7;
            atomicAdd(&h[bk[u]], 1);
        } else {
            bk[u] = -1;
        }
    }
    __syncthreads();
    for (int i = tid; i < NBUCK; i += 1024) {
        base[i] = h[i] ? atomicAdd(&bcur[i], h[i]) : 0;
        h[i] = 0;  // reuse as local cursor
    }
    __syncthreads();
#pragma unroll
    for (int u = 0; u < 4; ++u) {
        if (bk[u] >= 0) {
            const int pos = base[bk[u]] + atomicAdd(&h[bk[u]], 1);
            packed[pos] = val[u];
        }
    }
}

// One block per bucket: LDS 128-bin hist + scan -> per-node row_start/row_end;
// LDS-cursor scatter of u16 srcs into the bucket's contiguous region.
__global__ __launch_bounds__(512) void build_rows(const unsigned int* __restrict__ packed,
                                                  const int* __restrict__ bcur,
                                                  int* __restrict__ row_start,
                                                  int* __restrict__ row_end,
                                                  unsigned short* __restrict__ ssrc) {
    __shared__ int lh[128];
    __shared__ int lc[128];
    __shared__ int htot;
    const int b = blockIdx.x;
    const int gbase = b * BCAP, gend = bcur[b];
    const int tid = threadIdx.x;
    if (tid < 128) lh[tid] = 0;
    __syncthreads();
    for (int i = gbase + tid; i < gend; i += 512)
        atomicAdd(&lh[(packed[i] >> 16) & 127], 1);
    __syncthreads();
    int v = 0, incl = 0;
    if (tid < 128) {
        const int lane = tid & 63;
        v = lh[tid];
        incl = v;
#pragma unroll
        for (int off = 1; off < 64; off <<= 1) {
            int t = __shfl_up(incl, off);
            if (lane >= off) incl += t;
        }
        if (tid == 63) htot = incl;
    }
    __syncthreads();
    if (tid < 128) {
        const int excl = incl - v + ((tid >= 64) ? htot : 0);
        lc[tid] = gbase + excl;
        const int node = b * 128 + tid;
        if (node < N_NODES) {
            row_start[node] = gbase + excl;
            row_end[node]   = gbase + excl + v;
        }
    }
    __syncthreads();
    for (int i = gbase + tid; i < gend; i += 512) {
        const unsigned int p = packed[i];
        const int pos = atomicAdd(&lc[(p >> 16) & 127], 1);
        ssrc[pos] = (unsigned short)(p & 0xffffu);
    }
}

// 16 lanes per node (lane owns 8 features via ushort8 = 16B), 4 nodes per wave,
// edge loop unroll 8 -> up to 32 row-gathers in flight per wave.
__global__ __launch_bounds__(256) void aggregate_mean_bf16(
    const unsigned short* __restrict__ featb, const int* __restrict__ row_start,
    const int* __restrict__ row_end, const unsigned short* __restrict__ ssrc,
    unsigned short* __restrict__ aggb) {
    const int node = blockIdx.x * 16 + (threadIdx.x >> 4);
    const int lq = threadIdx.x & 15;
    if (node >= N_NODES) return;
    const int beg = row_start[node], end = row_end[node];
    float acc0[8], acc1[8];
#pragma unroll
    for (int f = 0; f < 8; ++f) { acc0[f] = 0.f; acc1[f] = 0.f; }

    int j = beg;
    for (; j + 7 < end; j += 8) {
        short8 v[8];
#pragma unroll
        for (int u = 0; u < 8; ++u) {
            const int s = ssrc[j + u];
            v[u] = *reinterpret_cast<const short8*>(&featb[(size_t)s * HIDDEN + 8 * lq]);
        }
#pragma unroll
        for (int u = 0; u < 8; ++u) {
            float* a = (u & 1) ? acc1 : acc0;
#pragma unroll
            for (int f = 0; f < 8; ++f) a[f] += bf2f((unsigned short)v[u][f]);
        }
    }
    if (j + 3 < end) {
        short8 v[4];
#pragma unroll
        for (int u = 0; u < 4; ++u) {
            const int s = ssrc[j + u];
            v[u] = *reinterpret_cast<const short8*>(&featb[(size_t)s * HIDDEN + 8 * lq]);
        }
#pragma unroll
        for (int u = 0; u < 4; ++u) {
            float* a = (u & 1) ? acc1 : acc0;
#pragma unroll
            for (int f = 0; f < 8; ++f) a[f] += bf2f((unsigned short)v[u][f]);
        }
        j += 4;
    }
    for (; j < end; ++j) {
        const int s = ssrc[j];
        const short8 v = *reinterpret_cast<const short8*>(&featb[(size_t)s * HIDDEN + 8 * lq]);
#pragma unroll
        for (int f = 0; f < 8; ++f) acc0[f] += bf2f((unsigned short)v[f]);
    }
    const int d = end - beg;
    const float inv = d ? 1.0f / (float)d : 0.0f;
    short8 o;
#pragma unroll
    for (int f = 0; f < 8; ++f) o[f] = (short)f2bf((acc0[f] + acc1[f]) * inv);
    *reinterpret_cast<short8*>(&aggb[(size_t)node * HIDDEN + 8 * lq]) = o;
}

// out[n][t] = relu?( sum_k aggb[n][k]*Wl[t][k] + xb[n][k]*Wr[t][k] + b[t] )
// 4 waves/block (2M x 2N), 64-row x 128-col tile, K=256 in 8 steps of 32.
// (R13 tried 32-row tiles for 2x occupancy: regressed — service-rate-bound,
// not TLP-starved. 64-row is the best measured configuration.)
// Depth-1 software pipeline (R11: neutral, kept — no cost).
// Layer 1 (WRITE_BF16_RELU=1) writes bf16 IN-PLACE over xb: each block reads
// only its own 64 rows (k-loop) before its epilogue stores -> no hazard.
template <int WRITE_BF16_RELU>
__global__ __launch_bounds__(256) void mfma_linear(
    const unsigned short* aggb, const unsigned short* xb,
    const unsigned short* __restrict__ Wp, const float* __restrict__ bias,
    unsigned short* out_b, float* out_f) {
    const int lane = threadIdx.x & 63;
    const int wave = threadIdx.x >> 6;
    const int wm = wave >> 1, wn = wave & 1;
    const int rowbase = blockIdx.x * 64 + wm * 32;
    const int colbase = wn * 64;
    const int l15 = lane & 15, l4 = lane >> 4;

    // clamped row addresses (constant across ks)
    size_t rowoff[2];
#pragma unroll
    for (int m = 0; m < 2; ++m) {
        int row = rowbase + m * 16 + l15;
        if (row >= N_NODES) row = N_NODES - 1;
        rowoff[m] = (size_t)row * HIDDEN;
    }
    const unsigned short* wpbase = &Wp[(((size_t)(colbase >> 4)) * 64 + lane) * 8];

    f32x4 acc[2][4];
#pragma unroll
    for (int m = 0; m < 2; ++m)
#pragma unroll
        for (int nf = 0; nf < 4; ++nf) acc[m][nf] = (f32x4){0.f, 0.f, 0.f, 0.f};

    short8 a_cur[2], a_nxt[2], b_cur[4], b_nxt[4];

#define LOAD_A(dst, ksv)                                                          \
    {                                                                             \
        const unsigned short* Asrc_ = ((ksv) < 4) ? aggb : xb;                    \
        const int koff_ = ((ksv) & 3) * 32 + l4 * 8;                              \
        dst[0] = *reinterpret_cast<const short8*>(&Asrc_[rowoff[0] + koff_]);     \
        dst[1] = *reinterpret_cast<const short8*>(&Asrc_[rowoff[1] + koff_]);     \
    }
#define LOAD_B(dst, ksv)                                                          \
    {                                                                             \
        _Pragma("unroll")                                                         \
        for (int nf_ = 0; nf_ < 4; ++nf_)                                         \
            dst[nf_] = *reinterpret_cast<const short8*>(                          \
                &wpbase[((size_t)(ksv)*8 + nf_) * 64 * 8]);                       \
    }

    LOAD_A(a_cur, 0);
    LOAD_B(b_cur, 0);

#pragma unroll
    for (int ks = 0; ks < 8; ++ks) {
        if (ks < 7) {
            LOAD_A(a_nxt, ks + 1);
            LOAD_B(b_nxt, ks + 1);
        }
#pragma unroll
        for (int nf = 0; nf < 4; ++nf) {
            acc[0][nf] = __builtin_amdgcn_mfma_f32_16x16x32_bf16(a_cur[0], b_cur[nf], acc[0][nf], 0, 0, 0);
            acc[1][nf] = __builtin_amdgcn_mfma_f32_16x16x32_bf16(a_cur[1], b_cur[nf], acc[1][nf], 0, 0, 0);
        }
        if (ks < 7) {
#pragma unroll
            for (int m = 0; m < 2; ++m) a_cur[m] = a_nxt[m];
#pragma unroll
            for (int nf = 0; nf < 4; ++nf) b_cur[nf] = b_nxt[nf];
        }
    }
#undef LOAD_A
#undef LOAD_B

#pragma unroll
    for (int nf = 0; nf < 4; ++nf) {
        const int col = colbase + nf * 16 + l15;
        const float bv = bias[col];
#pragma unroll
        for (int m = 0; m < 2; ++m) {
#pragma unroll
            for (int r = 0; r < 4; ++r) {
                const int row = rowbase + m * 16 + l4 * 4 + r;
                if (row < N_NODES) {
                    float v = acc[m][nf][r] + bv;
                    if (WRITE_BF16_RELU) {
                        v = fmaxf(v, 0.0f);
                        out_b[(size_t)row * HIDDEN + col] = f2bf(v);
                    } else {
                        out_f[(size_t)row * HIDDEN + col] = v;
                    }
                }
            }
        }
    }
}

extern "C" void kernel_launch(void* const* d_in, const int* in_sizes, int n_in,
                              void* d_out, int out_size, void* d_ws, size_t ws_size,
                              hipStream_t stream) {
    const float* x   = (const float*)d_in[0];
    const int*   ei  = (const int*)d_in[1];
    const float* W1l = (const float*)d_in[2];
    const float* b1  = (const float*)d_in[3];
    const float* W1r = (const float*)d_in[4];
    const float* W2l = (const float*)d_in[5];
    const float* b2  = (const float*)d_in[6];
    const float* W2r = (const float*)d_in[7];

    const int E = in_sizes[1] / 2;
    const int* src = ei;
    const int* dst = ei + E;

    // ---- workspace layout (all sections 16B aligned) ----
    int* iws        = (int*)d_ws;
    int* bcur       = iws;                       // @0      391 (pad 400)
    int* row_start  = iws + 400;                 // @400    50000
    int* row_end    = iws + 50400;               // @50400  50000
    unsigned int* packed = (unsigned int*)(iws + 100400);          // NBUCK*BCAP u32
    unsigned short* ssrc = (unsigned short*)(iws + 100400 + NBUCK * BCAP);  // NBUCK*BCAP u16
    unsigned short* xb   = ssrc + (size_t)NBUCK * BCAP;  // 6.4M bf16 (h overwrites in-place)
    unsigned short* aggb = xb + (size_t)N_NODES * HIDDEN;          // 6.4M bf16
    unsigned short* Wp1  = aggb + (size_t)N_NODES * HIDDEN;        // 32768 bf16
    unsigned short* Wp2  = Wp1 + 256 * HIDDEN;                     // 32768 bf16

    // prep: cast + pack + bcur init, one dispatch
    prep<<<CAST_BLOCKS + 256, 256, 0, stream>>>(x, xb, W1l, W1r, W2l, W2r, Wp1, Wp2, bcur);

    // ---- CSR build (shared by both layers): 2 kernels, no hist/scan ----
    partition_edges<<<(E + PCHUNK - 1) / PCHUNK, 1024, 0, stream>>>(src, dst, E, bcur, packed);
    build_rows<<<NBUCK, 512, 0, stream>>>(packed, bcur, row_start, row_end, ssrc);

    const int aggGrid = (N_NODES + 15) / 16;
    const int linGrid = (N_NODES + 63) / 64;

    // ---- layer 1 ----
    aggregate_mean_bf16<<<aggGrid, 256, 0, stream>>>(xb, row_start, row_end, ssrc, aggb);
    mfma_linear<1><<<linGrid, 256, 0, stream>>>(aggb, xb, Wp1, b1, xb, nullptr);

    // ---- layer 2 ----
    aggregate_mean_bf16<<<aggGrid, 256, 0, stream>>>(xb, row_start, row_end, ssrc, aggb);
    mfma_linear<0><<<linGrid, 256, 0, stream>>>(aggb, xb, Wp2, b2, nullptr, (float*)d_out);
}